// Round 14
// baseline (252.428 us; speedup 1.0000x reference)
//
#include <hip/hip_runtime.h>
#include <hip/hip_fp16.h>
#include <math.h>

#define Bn 4
#define Cn 96
#define Hn 128
#define Wn 128
#define Ln (Hn*Wn)      // 16384
#define Kn 2
#define Rn 6
#define SC 16           // scan chunk length
#define NCH (Ln/SC)     // 1024 chunks per (b,k)

__device__ __forceinline__ float siluf(float x) { return x / (1.f + __expf(-x)); }
// native-instruction softplus: log1pf is a slow libm polynomial; __logf(1+e)
// is v_log_f32 with abs err < 1e-7 over our range (tolerance 2.5e-2).
__device__ __forceinline__ float softplusf(float x) {
    return fmaxf(x, 0.f) + __logf(1.f + __expf(-fabsf(x)));
}

// ---------------------------------------------------------------------------
// NUMERICS / DETERMINISM LEDGER (empirical):
//   fp32 pipeline + f-fp16 (R1/R3/R13)   = 0.001953125, BIT-STABLE. PASSED.
//   + f16-MFMA out_proj (R8/R12 family)  = 0.0117-0.0273, RUN-TO-RUN
//     NONDETERMINISTIC -> ABANDONED.  zs/y0 fp16: FAILED (0.031-0.037).
// R14 delta vs R13 (238.3 us): k_inproj tile 128->64 pos, grid 512->1024
// (2->4 blocks/CU; R13 counters: top dispatch inproj 51.5us, Occupancy 17%,
// VALUBusy 42% -- residency-capped at exactly 2 blocks/CU).  Bit-identical:
// each output's fmaf chain over k is unchanged, only block ownership moves.
// ---------------------------------------------------------------------------

// ---------------------------------------------------------------------------
// Kernel A: in_proj GEMM, fp32 vector.  Tile 64 pos x 192 out, K=96 in
// 3 chunks of 32.  LDS 33.3KB -> 4 blocks/CU; acc 48 regs/thread.
// x (B,C,L) -> xc (B,L,C) fp32, zs = silu(z) (B,L,C) fp32.
// ---------------------------------------------------------------------------
__global__ __launch_bounds__(256, 4) void k_inproj(
    const float* __restrict__ x, const float* __restrict__ ipw,
    float* __restrict__ xc, float* __restrict__ zs)
{
    __shared__ float smem[2048 + 6272];  // xls 32x64 (8KB) + wls 32x196 (25KB)
    float* xls = smem;
    float* wls = smem + 2048;
    float* stage = smem;                 // epilogue [64][100] = 6400 <= 8320

    const int t  = threadIdx.x;
    const int b  = blockIdx.x >> 8;
    const int l0 = (blockIdx.x & 255) << 6;
    const int tx = t & 15;               // 4 positions: tx*4+j
    const int ty = t >> 4;               // 12 outputs: ty*12+i

    float acc[12][4];
#pragma unroll
    for (int i = 0; i < 12; ++i)
#pragma unroll
        for (int j = 0; j < 4; ++j) acc[i][j] = 0.f;

    const float* xbase = x + (size_t)b * Cn * Ln + l0;

    for (int k0 = 0; k0 < Cn; k0 += 32) {
        if (k0) __syncthreads();
        // x chunk: 32x64 floats = 512 float4, 2 per thread, coalesced
        {
            int idx = t;
#pragma unroll
            for (int q = 0; q < 2; ++q, idx += 256) {
                int k = idx >> 4, p4 = idx & 15;
                *(float4*)&xls[k * 64 + p4 * 4] =
                    *(const float4*)&xbase[(size_t)(k0 + k) * Ln + p4 * 4];
            }
        }
        // w chunk: 32x192 floats (ipw is 73KB, L2-hot across 1024 blocks)
        for (int idx = t; idx < 32 * 192; idx += 256) {
            int o = idx % 192, k = idx / 192;
            wls[k * 196 + o] = ipw[o * Cn + k0 + k];
        }
        __syncthreads();

#pragma unroll 2
        for (int kk = 0; kk < 32; ++kk) {
            float4 xv0 = *(const float4*)&xls[kk * 64 + tx * 4];
            const float* wrow = &wls[kk * 196 + ty * 12];
            float4 w0 = *(const float4*)&wrow[0];
            float4 w1 = *(const float4*)&wrow[4];
            float4 w2 = *(const float4*)&wrow[8];
            float wv[12] = {w0.x,w0.y,w0.z,w0.w,w1.x,w1.y,w1.z,w1.w,w2.x,w2.y,w2.z,w2.w};
            float xa[4]  = {xv0.x,xv0.y,xv0.z,xv0.w};
#pragma unroll
            for (int i = 0; i < 12; ++i)
#pragma unroll
                for (int j = 0; j < 4; ++j)
                    acc[i][j] = fmaf(wv[i], xa[j], acc[i][j]);
        }
    }

    // ---- epilogue: LDS-staged coalesced stores, {xc, zs} ----
    const size_t tilebase = (size_t)b * Ln + l0;
    __syncthreads();
    if (ty < 8) {
#pragma unroll
        for (int j = 0; j < 4; ++j)
#pragma unroll
            for (int i = 0; i < 12; ++i)
                stage[(tx * 4 + j) * 100 + ty * 12 + i] = acc[i][j];
    }
    __syncthreads();
    {
        float4* dst = (float4*)(xc + tilebase * Cn);
        for (int idx = t; idx < 1536; idx += 256) {
            int p = idx / 24, c4 = idx % 24;
            dst[idx] = *(const float4*)&stage[p * 100 + c4 * 4];
        }
    }
    __syncthreads();
    if (ty >= 8) {
#pragma unroll
        for (int j = 0; j < 4; ++j)
#pragma unroll
            for (int i = 0; i < 12; ++i)
                stage[(tx * 4 + j) * 100 + (ty - 8) * 12 + i] = siluf(acc[i][j]);
    }
    __syncthreads();
    {
        float4* dst = (float4*)(zs + tilebase * Cn);
        for (int idx = t; idx < 1536; idx += 256) {
            int p = idx / 24, c4 = idx % 24;
            dst[idx] = *(const float4*)&stage[p * 100 + c4 * 4];
        }
    }
}

// ---------------------------------------------------------------------------
// Kernel B: depthwise 3x3 conv (SAME) + bias + SiLU, float4 over channels.
// ---------------------------------------------------------------------------
__global__ __launch_bounds__(256) void k_conv(
    const float* __restrict__ xc, const float* __restrict__ cw,
    const float* __restrict__ cb, float* __restrict__ u)
{
    __shared__ float cws[9 * 96];   // [tap][c]
    for (int i = threadIdx.x; i < 864; i += 256) {
        int cc = i % 96, tap = i / 96;
        cws[tap * 96 + cc] = cw[cc * 9 + tap];
    }
    __syncthreads();

    const int e   = blockIdx.x * 256 + threadIdx.x;
    const int c4  = e % 24;
    const int pos = e / 24;
    const int l   = pos % Ln;
    const int b   = pos / Ln;
    const int h   = l >> 7, w = l & 127;
    const int c   = c4 * 4;

    float4 acc = *(const float4*)&cb[c];
#pragma unroll
    for (int dh = -1; dh <= 1; ++dh) {
        int hh = h + dh;
        if (hh < 0 || hh >= Hn) continue;
#pragma unroll
        for (int dw = -1; dw <= 1; ++dw) {
            int ww = w + dw;
            if (ww < 0 || ww >= Wn) continue;
            float4 wv = *(const float4*)&cws[((dh + 1) * 3 + (dw + 1)) * 96 + c];
            float4 xv = *(const float4*)&xc[((size_t)b * Ln + (hh << 7) + ww) * Cn + c];
            acc.x = fmaf(wv.x, xv.x, acc.x);
            acc.y = fmaf(wv.y, xv.y, acc.y);
            acc.z = fmaf(wv.z, xv.z, acc.z);
            acc.w = fmaf(wv.w, xv.w, acc.w);
        }
    }
    float4 r;
    r.x = siluf(acc.x); r.y = siluf(acc.y); r.z = siluf(acc.z); r.w = siluf(acc.w);
    *(float4*)&u[((size_t)b * Ln + l) * Cn + c] = r;
}

// ---------------------------------------------------------------------------
// Kernel C (k_part1): R13-proven (GEMV broadcast remap, fp32 y0, f fp16).
// ---------------------------------------------------------------------------
__global__ __launch_bounds__(384, 4) void k_part1(
    const float* __restrict__ u, const float* __restrict__ xpw,
    const float* __restrict__ dtw, const float* __restrict__ dtb,
    const float* __restrict__ Alogs, const float* __restrict__ Ds,
    float* __restrict__ Pc, float* __restrict__ Qc,
    float* __restrict__ y0, __half* __restrict__ f)
{
    __shared__ float uls[32 * 100];  // [p][c] pad 100; reused as y-merge buffer
    __shared__ float xd[32 * 16];    // [p][dd] dd=k*8+d
    __shared__ float dsum[96];
    const int t  = threadIdx.x;
    const int j  = blockIdx.x & 511;
    const int b  = blockIdx.x >> 9;
    const int l0 = j << 5;

    {
        const float4* up4 = (const float4*)(u + ((size_t)b * Ln + l0) * Cn);
        for (int e4 = t; e4 < 768; e4 += 384) {
            int p = e4 / 24, c4 = e4 % 24;
            *(float4*)&uls[p * 100 + c4 * 4] = up4[e4];
        }
    }
    if (t < 96) dsum[t] = Ds[t] + Ds[Cn + t];
    __syncthreads();   // all u loads in LDS before any f-store below (alias!)

    for (int dp = t; dp < 512; dp += 384) {
        int p = dp & 31, dd = dp >> 5;     // broadcast-friendly remap
        const float4* wr = (const float4*)(xpw + dd * Cn);
        const float4* ur = (const float4*)&uls[p * 100];
        float acc = 0.f;
#pragma unroll
        for (int c4 = 0; c4 < 24; ++c4) {
            float4 w = wr[c4], v = ur[c4];
            acc = fmaf(w.x, v.x, acc); acc = fmaf(w.y, v.y, acc);
            acc = fmaf(w.z, v.z, acc); acc = fmaf(w.w, v.w, acc);
        }
        xd[p * 16 + dd] = acc;
    }
    __syncthreads();

    const int c  = t % 96;
    const int ci = (t / 96) & 1;
    const int k  = t / 192;
    const int bk = b * Kn + k;
    const float Av = -__expf(Alogs[k * Cn + c]);
    const float bias = dtb[k * Cn + c];
    const float dsc = dsum[c];
    float dtwr[Rn];
#pragma unroll
    for (int r = 0; r < Rn; ++r) dtwr[r] = dtw[(k * Cn + c) * Rn + r];

    const int chunk = (k == 0) ? (2 * j + ci) : (1022 - 2 * j + ci);
    const int xoff = k * 8;
    __half* fkc = f + ((size_t)(b * Ln + l0) * 2 + k) * Cn + c;

    float h = 0.f, cp = 1.f;
    float yreg[SC];
#pragma unroll
    for (int hf = 0; hf < 2; ++hf) {
        float dAv[8], dBu[8], Cl[8], uv[8];
#pragma unroll
        for (int i = 0; i < 8; ++i) {
            const int ii = hf * 8 + i;
            const int p = (k == 0) ? (ci * 16 + ii) : ((1 - ci) * 16 + (15 - ii));
            const float* xr = &xd[p * 16 + xoff];
            float de = bias;
#pragma unroll
            for (int r = 0; r < Rn; ++r) de = fmaf(dtwr[r], xr[r], de);
            de = softplusf(de);
            uv[i]  = uls[p * 100 + c];
            dAv[i] = __expf(de * Av);
            dBu[i] = de * uv[i] * xr[6];
            Cl[i]  = xr[7];
        }
#pragma unroll
        for (int i = 0; i < 8; ++i) {
            const int ii = hf * 8 + i;
            const int p = (k == 0) ? (ci * 16 + ii) : ((1 - ci) * 16 + (15 - ii));
            h  = fmaf(dAv[i], h, dBu[i]);
            cp *= dAv[i];
            yreg[ii] = (k == 0) ? fmaf(dsc, uv[i], h * Cl[i]) : (h * Cl[i]);
            fkc[(size_t)p * (2 * Cn)] = __float2half(cp * Cl[i]);
        }
    }
    {
        const size_t cidx = ((size_t)bk * NCH + chunk) * Cn + c;
        Pc[cidx] = cp;
        Qc[cidx] = h;
    }

    __syncthreads();   // all uls reads done
    if (k == 0) {
#pragma unroll
        for (int i = 0; i < SC; ++i) {
            int p = ci * 16 + i;
            uls[p * 100 + c] = yreg[i];
        }
    }
    __syncthreads();
    if (k == 1) {
#pragma unroll
        for (int i = 0; i < SC; ++i) {
            int p = (1 - ci) * 16 + (15 - i);
            uls[p * 100 + c] += yreg[i];
        }
    }
    __syncthreads();
    {
        float4* y4 = (float4*)(y0 + ((size_t)b * Ln + l0) * Cn);
        for (int e4 = t; e4 < 768; e4 += 384) {
            int p = e4 / 24, c4 = e4 % 24;
            y4[e4] = *(const float4*)&uls[p * 100 + c4 * 4];
        }
    }
}

// ---------------------------------------------------------------------------
// Kernel D: hierarchical carry scan (unchanged). 768 series x 1024 chunks.
// ---------------------------------------------------------------------------
__global__ __launch_bounds__(1024) void k_scan2(
    const float* __restrict__ Pc, const float* __restrict__ Qc,
    float* __restrict__ hinit)
{
    __shared__ float Pg[32][33], Qg[32][33], gini[32][33];
    const int bk    = blockIdx.x / 3;
    const int cbase = (blockIdx.x % 3) * 32;
    const int t = threadIdx.x;
    const int c = t & 31, g = t >> 5;

    const size_t base = ((size_t)bk * NCH + g * 32) * Cn + cbase + c;
    float P = 1.f, Q = 0.f;
    for (int j = 0; j < 32; ++j) {
        size_t idx = base + (size_t)j * Cn;
        float p_ = Pc[idx], q_ = Qc[idx];
        Q = fmaf(p_, Q, q_);
        P *= p_;
    }
    Pg[g][c] = P; Qg[g][c] = Q;
    __syncthreads();
    if (t < 32) {
        float h = 0.f;
        for (int gg = 0; gg < 32; ++gg) {
            gini[gg][t] = h;
            h = fmaf(Pg[gg][t], h, Qg[gg][t]);
        }
    }
    __syncthreads();
    float h = gini[g][c];
    for (int j = 0; j < 32; ++j) {
        size_t idx = base + (size_t)j * Cn;
        hinit[idx] = h;
        h = fmaf(Pc[idx], h, Qc[idx]);
    }
}

// ---------------------------------------------------------------------------
// Kernel E (k_merge): streaming merge + LN + gate + fused fp32 out_proj GEMM
// (R13-proven, deterministic 0.00195).  No g round-trip to HBM.
// ---------------------------------------------------------------------------
__global__ __launch_bounds__(512) void k_merge(
    const float* __restrict__ y0, const __half* __restrict__ f,
    const float* __restrict__ hinit, const float* __restrict__ zs,
    const float* __restrict__ onw, const float* __restrict__ onb,
    const float* __restrict__ opw, const float* __restrict__ scw,
    float* __restrict__ out)
{
    __shared__ float gt[64 * 104];   // y -> gated g -> reused as outT[o][68]
    __shared__ float wls[96 * 36];   // opw chunk [o][32] pad 36
    __shared__ float h0s[4 * 96], h1s[4 * 96];
    __shared__ float mu[64], isd[64];
    const int t  = threadIdx.x;
    const int j  = blockIdx.x & 255;
    const int b  = blockIdx.x >> 8;
    const int l0 = j << 6;

    for (int idx = t; idx < 768; idx += 512) {
        if (idx < 384) {
            int q = idx / 96, c = idx % 96;
            h0s[q * 96 + c] = hinit[((size_t)(b * 2 + 0) * NCH + 4 * j + q) * Cn + c];
        } else {
            int i2 = idx - 384;
            int q = i2 / 96, c = i2 % 96;
            h1s[q * 96 + c] = hinit[((size_t)(b * 2 + 1) * NCH + (1023 - 4 * j - q)) * Cn + c];
        }
    }
    __syncthreads();

    // elementwise merge: y = y0 + h0*f0 + h1*f1  -> gt[p][c]
    {
        const float4* y4 = (const float4*)(y0 + ((size_t)b * Ln + l0) * Cn);
        const __half* fb = f + (size_t)(b * Ln + l0) * 2 * Cn;
        for (int e4 = t; e4 < 1536; e4 += 512) {
            int p = e4 / 24, c4 = e4 % 24;
            float4 yv = y4[e4];
            const __half* fp0 = fb + (size_t)p * (2 * Cn) + c4 * 4;
            const __half2* f0h = (const __half2*)fp0;
            const __half2* f1h = (const __half2*)(fp0 + Cn);
            float2 fa0 = __half22float2(f0h[0]);
            float2 fa1 = __half22float2(f0h[1]);
            float2 fb0 = __half22float2(f1h[0]);
            float2 fb1 = __half22float2(f1h[1]);
            const float4 h0v = *(const float4*)&h0s[(p >> 4) * 96 + c4 * 4];
            const float4 h1v = *(const float4*)&h1s[(p >> 4) * 96 + c4 * 4];
            yv.x = fmaf(h0v.x, fa0.x, fmaf(h1v.x, fb0.x, yv.x));
            yv.y = fmaf(h0v.y, fa0.y, fmaf(h1v.y, fb0.y, yv.y));
            yv.z = fmaf(h0v.z, fa1.x, fmaf(h1v.z, fb1.x, yv.z));
            yv.w = fmaf(h0v.w, fa1.y, fmaf(h1v.w, fb1.y, yv.w));
            *(float4*)&gt[p * 104 + c4 * 4] = yv;
        }
    }
    __syncthreads();

    if (t < 256) {
        const int p = t >> 2, q = t & 3;
        const float4* row = (const float4*)&gt[p * 104 + q * 24];
        float s = 0.f, ss = 0.f;
#pragma unroll
        for (int i = 0; i < 6; ++i) {
            float4 v = row[i];
            s  += v.x + v.y + v.z + v.w;
            ss += v.x*v.x + v.y*v.y + v.z*v.z + v.w*v.w;
        }
        s  += __shfl_xor(s, 1);  s  += __shfl_xor(s, 2);
        ss += __shfl_xor(ss, 1); ss += __shfl_xor(ss, 2);
        if (q == 0) {
            float m = s * (1.f / Cn);
            mu[p] = m;
            isd[p] = rsqrtf(ss * (1.f / Cn) - m * m + 1e-5f);
        }
    }
    __syncthreads();

    // gate in place: gt[p][c] = ((y-mu)*isd*w + b) * silu-z
    {
        const float4* zp4 = (const float4*)(zs + ((size_t)b * Ln + l0) * Cn);
        const float4* w4  = (const float4*)onw;
        const float4* b4  = (const float4*)onb;
        for (int e4 = t; e4 < 1536; e4 += 512) {
            int p = e4 / 24, c4 = e4 % 24;
            float4 v = *(const float4*)&gt[p * 104 + c4 * 4];
            float4 wv = w4[c4], bv = b4[c4], zv = zp4[e4];
            float m = mu[p], is = isd[p];
            v.x = ((v.x - m) * is * wv.x + bv.x) * zv.x;
            v.y = ((v.y - m) * is * wv.y + bv.y) * zv.y;
            v.z = ((v.z - m) * is * wv.z + bv.z) * zv.z;
            v.w = ((v.w - m) * is * wv.w + bv.w) * zv.w;
            *(float4*)&gt[p * 104 + c4 * 4] = v;
        }
    }

    // fused out_proj GEMM (fp32 vector): out(o,p) = sum_c gt[p][c]*opw[o][c]
    const int og = t & 31, pg = t >> 5;
    float acc[3][4];
#pragma unroll
    for (int i = 0; i < 3; ++i)
#pragma unroll
        for (int r = 0; r < 4; ++r) acc[i][r] = 0.f;

    for (int k0 = 0; k0 < Cn; k0 += 32) {
        __syncthreads();
        for (int e4 = t; e4 < 768; e4 += 512) {
            int o = e4 >> 3, c4 = e4 & 7;
            *(float4*)&wls[o * 36 + c4 * 4] = *(const float4*)&opw[o * Cn + k0 + c4 * 4];
        }
        __syncthreads();
#pragma unroll
        for (int c4 = 0; c4 < 8; ++c4) {
            float4 w0 = *(const float4*)&wls[(og * 3 + 0) * 36 + c4 * 4];
            float4 w1 = *(const float4*)&wls[(og * 3 + 1) * 36 + c4 * 4];
            float4 w2 = *(const float4*)&wls[(og * 3 + 2) * 36 + c4 * 4];
            float4 g0 = *(const float4*)&gt[(pg * 4 + 0) * 104 + k0 + c4 * 4];
            float4 g1 = *(const float4*)&gt[(pg * 4 + 1) * 104 + k0 + c4 * 4];
            float4 g2 = *(const float4*)&gt[(pg * 4 + 2) * 104 + k0 + c4 * 4];
            float4 g3 = *(const float4*)&gt[(pg * 4 + 3) * 104 + k0 + c4 * 4];
#define ACC1(i, wv, r, gv) \
            acc[i][r] = fmaf(wv.x, gv.x, acc[i][r]); \
            acc[i][r] = fmaf(wv.y, gv.y, acc[i][r]); \
            acc[i][r] = fmaf(wv.z, gv.z, acc[i][r]); \
            acc[i][r] = fmaf(wv.w, gv.w, acc[i][r]);
            ACC1(0, w0, 0, g0) ACC1(0, w0, 1, g1) ACC1(0, w0, 2, g2) ACC1(0, w0, 3, g3)
            ACC1(1, w1, 0, g0) ACC1(1, w1, 1, g1) ACC1(1, w1, 2, g2) ACC1(1, w1, 3, g3)
            ACC1(2, w2, 0, g0) ACC1(2, w2, 1, g1) ACC1(2, w2, 2, g2) ACC1(2, w2, 3, g3)
#undef ACC1
        }
    }

    __syncthreads();   // all gt reads done -> reuse gt as outT[o][68]
#pragma unroll
    for (int i = 0; i < 3; ++i)
#pragma unroll
        for (int r = 0; r < 4; ++r)
            gt[(og * 3 + i) * 68 + pg * 4 + r] = acc[i][r];
    __syncthreads();

    {
        float* ob = out + (size_t)b * Cn * Ln + l0;
        for (int e4 = t; e4 < 1536; e4 += 512) {
            int o = e4 >> 4, p4 = e4 & 15;
            float4 v = *(const float4*)&gt[o * 68 + p4 * 4];
            float sc = scw[o];
            v.x *= sc; v.y *= sc; v.z *= sc; v.w *= sc;
            *(float4*)&ob[(size_t)o * Ln + p4 * 4] = v;
        }
    }
}

// ---------------------------------------------------------------------------
extern "C" void kernel_launch(void* const* d_in, const int* in_sizes, int n_in,
                              void* d_out, int out_size, void* d_ws, size_t ws_size,
                              hipStream_t stream)
{
    const float* x     = (const float*)d_in[0];
    const float* ipw   = (const float*)d_in[1];
    const float* cw    = (const float*)d_in[2];
    const float* cb    = (const float*)d_in[3];
    const float* xpw   = (const float*)d_in[4];
    const float* dtw   = (const float*)d_in[5];
    const float* dtb   = (const float*)d_in[6];
    const float* Alogs = (const float*)d_in[7];
    const float* Ds    = (const float*)d_in[8];
    const float* onw   = (const float*)d_in[9];
    const float* onb   = (const float*)d_in[10];
    const float* opw   = (const float*)d_in[11];
    const float* scw   = (const float*)d_in[12];
    float* out = (float*)d_out;

    // Workspace (R13-proven layout, 3A + 3S):
    float* wsp = (float*)d_ws;
    size_t off = 0;
    // xc dead after k_conv -> y0 aliases it
    float* xc   = wsp + off;
    float* y0   = wsp + off; off += (size_t)Bn * Ln * Cn;         // 6.29M
    float* zs   = wsp + off; off += (size_t)Bn * Ln * Cn;         // 6.29M
    float* u    = wsp + off; off += (size_t)Bn * Ln * Cn;         // 6.29M
    // f (fp16, [b][l][k][c]) overlays u byte-exactly per position; each part1
    // block consumes its own u range into LDS (barrier) before overwriting it.
    __half* f   = (__half*)u;
    float* Pc    = wsp + off; off += (size_t)Bn * Kn * NCH * Cn;  // 0.79M
    float* Qc    = wsp + off; off += (size_t)Bn * Kn * NCH * Cn;
    float* hinit = wsp + off; off += (size_t)Bn * Kn * NCH * Cn;

    k_inproj<<<Bn * 256, 256, 0, stream>>>(x, ipw, xc, zs);
    k_conv  <<<(Bn * Ln * 24) / 256, 256, 0, stream>>>(xc, cw, cb, u);
    k_part1 <<<Bn * 512, 384, 0, stream>>>(u, xpw, dtw, dtb, Alogs, Ds,
                                           Pc, Qc, y0, f);
    k_scan2 <<<24, 1024, 0, stream>>>(Pc, Qc, hinit);
    k_merge <<<Bn * 256, 512, 0, stream>>>(y0, f, hinit, zs, onw, onb,
                                           opw, scw, out);
}

// Round 15
// 245.099 us; speedup vs baseline: 1.0299x; 1.0299x over previous
//
#include <hip/hip_runtime.h>
#include <hip/hip_fp16.h>
#include <math.h>

#define Bn 4
#define Cn 96
#define Hn 128
#define Wn 128
#define Ln (Hn*Wn)      // 16384
#define Kn 2
#define Rn 6
#define SC 16           // scan chunk length
#define NCH (Ln/SC)     // 1024 chunks per (b,k)

__device__ __forceinline__ float siluf(float x) { return x / (1.f + __expf(-x)); }
// native-instruction softplus: log1pf is a slow libm polynomial; __logf(1+e)
// is v_log_f32 with abs err < 1e-7 over our range (tolerance 2.5e-2).
__device__ __forceinline__ float softplusf(float x) {
    return fmaxf(x, 0.f) + __logf(1.f + __expf(-fabsf(x)));
}

// ---------------------------------------------------------------------------
// NUMERICS / DETERMINISM LEDGER (empirical):
//   fp32 pipeline + f-fp16 (R1/R3/R13)   = 0.001953125, BIT-STABLE. PASSED.
//   f16-MFMA out_proj: NONDETERMINISTIC (0.0117-0.0273) -> ABANDONED.
//   zs/y0 fp16: FAILED (0.031-0.037) -> fp32 forever.
// SPEED LEDGER for k_inproj:
//   R13: 128pos x 192out, 256thr (8x12/thread), 2 blk/CU  = 51.5 us
//   R14: 64pos  x 192out, 256thr (4x12/thread), 4 blk/CU  = 66.4 us  WORSE
//   -> inner-loop LDS intensity (19.2 fma/b128-read) is load-bearing;
//      occupancy was NOT the limiter.
// R15: keep the 8x12 thread tile EXACTLY (bit-identical chains); split the
// 192 outputs across 2 blocks (128 thr each, half->xc, half->zs).  Same
// waves/CU but 4 independent barrier domains instead of 2, LDS 41.5->28.5KB,
// epilogue passes 4->2.
// ---------------------------------------------------------------------------

// ---------------------------------------------------------------------------
// Kernel A: in_proj GEMM, fp32 vector.  Block = 128 thr, tile 128 pos x
// 96 outs (half = blockIdx&1; 0 -> xc, 1 -> silu -> zs).
// ---------------------------------------------------------------------------
__global__ __launch_bounds__(128) void k_inproj(
    const float* __restrict__ x, const float* __restrict__ ipw,
    float* __restrict__ xc, float* __restrict__ zs)
{
    __shared__ float smem[4096 + 3200];  // xls 32x128 + wls 32x100
    float* xls = smem;
    float* wls = smem + 4096;
    float* stage = smem;                 // epilogue [64][100] = 6400 <= 7296

    const int t    = threadIdx.x;
    const int b    = blockIdx.x >> 8;
    const int l0   = ((blockIdx.x >> 1) & 127) << 7;
    const int half = blockIdx.x & 1;
    const int o0   = half * 96;
    const int tx = t & 15;               // 8 positions: tx*4+j, 64+tx*4+j
    const int ty = t >> 4;               // 12 outputs: ty*12+i (of this half)

    float acc[12][8];
#pragma unroll
    for (int i = 0; i < 12; ++i)
#pragma unroll
        for (int j = 0; j < 8; ++j) acc[i][j] = 0.f;

    const float* xbase = x + (size_t)b * Cn * Ln + l0;

    for (int k0 = 0; k0 < Cn; k0 += 32) {
        if (k0) __syncthreads();
        // x chunk: 32x128 floats = 1024 float4, 8 per thread, coalesced
        {
            int idx = t;
#pragma unroll
            for (int q = 0; q < 8; ++q, idx += 128) {
                int k = idx >> 5, p4 = idx & 31;
                *(float4*)&xls[k * 128 + p4 * 4] =
                    *(const float4*)&xbase[(size_t)(k0 + k) * Ln + p4 * 4];
            }
        }
        // w chunk: 32 x 96 floats (this half's outputs)
        for (int idx = t; idx < 32 * 96; idx += 128) {
            int o = idx % 96, k = idx / 96;
            wls[k * 100 + o] = ipw[(o0 + o) * Cn + k0 + k];
        }
        __syncthreads();

#pragma unroll 2
        for (int kk = 0; kk < 32; ++kk) {
            float4 xv0 = *(const float4*)&xls[kk * 128 + tx * 4];
            float4 xv1 = *(const float4*)&xls[kk * 128 + 64 + tx * 4];
            const float* wrow = &wls[kk * 100 + ty * 12];
            float4 w0 = *(const float4*)&wrow[0];
            float4 w1 = *(const float4*)&wrow[4];
            float4 w2 = *(const float4*)&wrow[8];
            float wv[12] = {w0.x,w0.y,w0.z,w0.w,w1.x,w1.y,w1.z,w1.w,w2.x,w2.y,w2.z,w2.w};
            float xa[8]  = {xv0.x,xv0.y,xv0.z,xv0.w,xv1.x,xv1.y,xv1.z,xv1.w};
#pragma unroll
            for (int i = 0; i < 12; ++i)
#pragma unroll
                for (int j = 0; j < 8; ++j)
                    acc[i][j] = fmaf(wv[i], xa[j], acc[i][j]);
        }
    }

    // ---- epilogue: 2 passes of 64 positions, one output array ----
    float* dstbase = half ? zs : xc;
    const size_t tilebase = (size_t)b * Ln + l0;
#pragma unroll
    for (int hf = 0; hf < 2; ++hf) {
        __syncthreads();
        // all 128 threads stage their 12x4 sub-block for this pos-half
#pragma unroll
        for (int j = 0; j < 4; ++j)
#pragma unroll
            for (int i = 0; i < 12; ++i)
                stage[(tx * 4 + j) * 100 + ty * 12 + i] = acc[i][hf * 4 + j];
        __syncthreads();
        {
            float* dst = dstbase + (tilebase + hf * 64) * Cn;
            for (int idx = t; idx < 1536; idx += 128) {
                int p = idx / 24, c4 = idx % 24;
                float4 v = *(const float4*)&stage[p * 100 + c4 * 4];
                if (half) {
                    v.x = siluf(v.x); v.y = siluf(v.y);
                    v.z = siluf(v.z); v.w = siluf(v.w);
                }
                *(float4*)&dst[(size_t)p * Cn + c4 * 4] = v;
            }
        }
    }
}

// ---------------------------------------------------------------------------
// Kernel B: depthwise 3x3 conv (SAME) + bias + SiLU, float4 over channels.
// ---------------------------------------------------------------------------
__global__ __launch_bounds__(256) void k_conv(
    const float* __restrict__ xc, const float* __restrict__ cw,
    const float* __restrict__ cb, float* __restrict__ u)
{
    __shared__ float cws[9 * 96];   // [tap][c]
    for (int i = threadIdx.x; i < 864; i += 256) {
        int cc = i % 96, tap = i / 96;
        cws[tap * 96 + cc] = cw[cc * 9 + tap];
    }
    __syncthreads();

    const int e   = blockIdx.x * 256 + threadIdx.x;
    const int c4  = e % 24;
    const int pos = e / 24;
    const int l   = pos % Ln;
    const int b   = pos / Ln;
    const int h   = l >> 7, w = l & 127;
    const int c   = c4 * 4;

    float4 acc = *(const float4*)&cb[c];
#pragma unroll
    for (int dh = -1; dh <= 1; ++dh) {
        int hh = h + dh;
        if (hh < 0 || hh >= Hn) continue;
#pragma unroll
        for (int dw = -1; dw <= 1; ++dw) {
            int ww = w + dw;
            if (ww < 0 || ww >= Wn) continue;
            float4 wv = *(const float4*)&cws[((dh + 1) * 3 + (dw + 1)) * 96 + c];
            float4 xv = *(const float4*)&xc[((size_t)b * Ln + (hh << 7) + ww) * Cn + c];
            acc.x = fmaf(wv.x, xv.x, acc.x);
            acc.y = fmaf(wv.y, xv.y, acc.y);
            acc.z = fmaf(wv.z, xv.z, acc.z);
            acc.w = fmaf(wv.w, xv.w, acc.w);
        }
    }
    float4 r;
    r.x = siluf(acc.x); r.y = siluf(acc.y); r.z = siluf(acc.z); r.w = siluf(acc.w);
    *(float4*)&u[((size_t)b * Ln + l) * Cn + c] = r;
}

// ---------------------------------------------------------------------------
// Kernel C (k_part1): R13-proven (GEMV broadcast remap, fp32 y0, f fp16).
// ---------------------------------------------------------------------------
__global__ __launch_bounds__(384, 4) void k_part1(
    const float* __restrict__ u, const float* __restrict__ xpw,
    const float* __restrict__ dtw, const float* __restrict__ dtb,
    const float* __restrict__ Alogs, const float* __restrict__ Ds,
    float* __restrict__ Pc, float* __restrict__ Qc,
    float* __restrict__ y0, __half* __restrict__ f)
{
    __shared__ float uls[32 * 100];  // [p][c] pad 100; reused as y-merge buffer
    __shared__ float xd[32 * 16];    // [p][dd] dd=k*8+d
    __shared__ float dsum[96];
    const int t  = threadIdx.x;
    const int j  = blockIdx.x & 511;
    const int b  = blockIdx.x >> 9;
    const int l0 = j << 5;

    {
        const float4* up4 = (const float4*)(u + ((size_t)b * Ln + l0) * Cn);
        for (int e4 = t; e4 < 768; e4 += 384) {
            int p = e4 / 24, c4 = e4 % 24;
            *(float4*)&uls[p * 100 + c4 * 4] = up4[e4];
        }
    }
    if (t < 96) dsum[t] = Ds[t] + Ds[Cn + t];
    __syncthreads();   // all u loads in LDS before any f-store below (alias!)

    for (int dp = t; dp < 512; dp += 384) {
        int p = dp & 31, dd = dp >> 5;     // broadcast-friendly remap
        const float4* wr = (const float4*)(xpw + dd * Cn);
        const float4* ur = (const float4*)&uls[p * 100];
        float acc = 0.f;
#pragma unroll
        for (int c4 = 0; c4 < 24; ++c4) {
            float4 w = wr[c4], v = ur[c4];
            acc = fmaf(w.x, v.x, acc); acc = fmaf(w.y, v.y, acc);
            acc = fmaf(w.z, v.z, acc); acc = fmaf(w.w, v.w, acc);
        }
        xd[p * 16 + dd] = acc;
    }
    __syncthreads();

    const int c  = t % 96;
    const int ci = (t / 96) & 1;
    const int k  = t / 192;
    const int bk = b * Kn + k;
    const float Av = -__expf(Alogs[k * Cn + c]);
    const float bias = dtb[k * Cn + c];
    const float dsc = dsum[c];
    float dtwr[Rn];
#pragma unroll
    for (int r = 0; r < Rn; ++r) dtwr[r] = dtw[(k * Cn + c) * Rn + r];

    const int chunk = (k == 0) ? (2 * j + ci) : (1022 - 2 * j + ci);
    const int xoff = k * 8;
    __half* fkc = f + ((size_t)(b * Ln + l0) * 2 + k) * Cn + c;

    float h = 0.f, cp = 1.f;
    float yreg[SC];
#pragma unroll
    for (int hf = 0; hf < 2; ++hf) {
        float dAv[8], dBu[8], Cl[8], uv[8];
#pragma unroll
        for (int i = 0; i < 8; ++i) {
            const int ii = hf * 8 + i;
            const int p = (k == 0) ? (ci * 16 + ii) : ((1 - ci) * 16 + (15 - ii));
            const float* xr = &xd[p * 16 + xoff];
            float de = bias;
#pragma unroll
            for (int r = 0; r < Rn; ++r) de = fmaf(dtwr[r], xr[r], de);
            de = softplusf(de);
            uv[i]  = uls[p * 100 + c];
            dAv[i] = __expf(de * Av);
            dBu[i] = de * uv[i] * xr[6];
            Cl[i]  = xr[7];
        }
#pragma unroll
        for (int i = 0; i < 8; ++i) {
            const int ii = hf * 8 + i;
            const int p = (k == 0) ? (ci * 16 + ii) : ((1 - ci) * 16 + (15 - ii));
            h  = fmaf(dAv[i], h, dBu[i]);
            cp *= dAv[i];
            yreg[ii] = (k == 0) ? fmaf(dsc, uv[i], h * Cl[i]) : (h * Cl[i]);
            fkc[(size_t)p * (2 * Cn)] = __float2half(cp * Cl[i]);
        }
    }
    {
        const size_t cidx = ((size_t)bk * NCH + chunk) * Cn + c;
        Pc[cidx] = cp;
        Qc[cidx] = h;
    }

    __syncthreads();   // all uls reads done
    if (k == 0) {
#pragma unroll
        for (int i = 0; i < SC; ++i) {
            int p = ci * 16 + i;
            uls[p * 100 + c] = yreg[i];
        }
    }
    __syncthreads();
    if (k == 1) {
#pragma unroll
        for (int i = 0; i < SC; ++i) {
            int p = (1 - ci) * 16 + (15 - i);
            uls[p * 100 + c] += yreg[i];
        }
    }
    __syncthreads();
    {
        float4* y4 = (float4*)(y0 + ((size_t)b * Ln + l0) * Cn);
        for (int e4 = t; e4 < 768; e4 += 384) {
            int p = e4 / 24, c4 = e4 % 24;
            y4[e4] = *(const float4*)&uls[p * 100 + c4 * 4];
        }
    }
}

// ---------------------------------------------------------------------------
// Kernel D: hierarchical carry scan (unchanged). 768 series x 1024 chunks.
// ---------------------------------------------------------------------------
__global__ __launch_bounds__(1024) void k_scan2(
    const float* __restrict__ Pc, const float* __restrict__ Qc,
    float* __restrict__ hinit)
{
    __shared__ float Pg[32][33], Qg[32][33], gini[32][33];
    const int bk    = blockIdx.x / 3;
    const int cbase = (blockIdx.x % 3) * 32;
    const int t = threadIdx.x;
    const int c = t & 31, g = t >> 5;

    const size_t base = ((size_t)bk * NCH + g * 32) * Cn + cbase + c;
    float P = 1.f, Q = 0.f;
    for (int j = 0; j < 32; ++j) {
        size_t idx = base + (size_t)j * Cn;
        float p_ = Pc[idx], q_ = Qc[idx];
        Q = fmaf(p_, Q, q_);
        P *= p_;
    }
    Pg[g][c] = P; Qg[g][c] = Q;
    __syncthreads();
    if (t < 32) {
        float h = 0.f;
        for (int gg = 0; gg < 32; ++gg) {
            gini[gg][t] = h;
            h = fmaf(Pg[gg][t], h, Qg[gg][t]);
        }
    }
    __syncthreads();
    float h = gini[g][c];
    for (int j = 0; j < 32; ++j) {
        size_t idx = base + (size_t)j * Cn;
        hinit[idx] = h;
        h = fmaf(Pc[idx], h, Qc[idx]);
    }
}

// ---------------------------------------------------------------------------
// Kernel E (k_merge): streaming merge + LN + gate + fused fp32 out_proj GEMM
// (R13-proven, deterministic 0.00195).  No g round-trip to HBM.
// ---------------------------------------------------------------------------
__global__ __launch_bounds__(512) void k_merge(
    const float* __restrict__ y0, const __half* __restrict__ f,
    const float* __restrict__ hinit, const float* __restrict__ zs,
    const float* __restrict__ onw, const float* __restrict__ onb,
    const float* __restrict__ opw, const float* __restrict__ scw,
    float* __restrict__ out)
{
    __shared__ float gt[64 * 104];   // y -> gated g -> reused as outT[o][68]
    __shared__ float wls[96 * 36];   // opw chunk [o][32] pad 36
    __shared__ float h0s[4 * 96], h1s[4 * 96];
    __shared__ float mu[64], isd[64];
    const int t  = threadIdx.x;
    const int j  = blockIdx.x & 255;
    const int b  = blockIdx.x >> 8;
    const int l0 = j << 6;

    for (int idx = t; idx < 768; idx += 512) {
        if (idx < 384) {
            int q = idx / 96, c = idx % 96;
            h0s[q * 96 + c] = hinit[((size_t)(b * 2 + 0) * NCH + 4 * j + q) * Cn + c];
        } else {
            int i2 = idx - 384;
            int q = i2 / 96, c = i2 % 96;
            h1s[q * 96 + c] = hinit[((size_t)(b * 2 + 1) * NCH + (1023 - 4 * j - q)) * Cn + c];
        }
    }
    __syncthreads();

    // elementwise merge: y = y0 + h0*f0 + h1*f1  -> gt[p][c]
    {
        const float4* y4 = (const float4*)(y0 + ((size_t)b * Ln + l0) * Cn);
        const __half* fb = f + (size_t)(b * Ln + l0) * 2 * Cn;
        for (int e4 = t; e4 < 1536; e4 += 512) {
            int p = e4 / 24, c4 = e4 % 24;
            float4 yv = y4[e4];
            const __half* fp0 = fb + (size_t)p * (2 * Cn) + c4 * 4;
            const __half2* f0h = (const __half2*)fp0;
            const __half2* f1h = (const __half2*)(fp0 + Cn);
            float2 fa0 = __half22float2(f0h[0]);
            float2 fa1 = __half22float2(f0h[1]);
            float2 fb0 = __half22float2(f1h[0]);
            float2 fb1 = __half22float2(f1h[1]);
            const float4 h0v = *(const float4*)&h0s[(p >> 4) * 96 + c4 * 4];
            const float4 h1v = *(const float4*)&h1s[(p >> 4) * 96 + c4 * 4];
            yv.x = fmaf(h0v.x, fa0.x, fmaf(h1v.x, fb0.x, yv.x));
            yv.y = fmaf(h0v.y, fa0.y, fmaf(h1v.y, fb0.y, yv.y));
            yv.z = fmaf(h0v.z, fa1.x, fmaf(h1v.z, fb1.x, yv.z));
            yv.w = fmaf(h0v.w, fa1.y, fmaf(h1v.w, fb1.y, yv.w));
            *(float4*)&gt[p * 104 + c4 * 4] = yv;
        }
    }
    __syncthreads();

    if (t < 256) {
        const int p = t >> 2, q = t & 3;
        const float4* row = (const float4*)&gt[p * 104 + q * 24];
        float s = 0.f, ss = 0.f;
#pragma unroll
        for (int i = 0; i < 6; ++i) {
            float4 v = row[i];
            s  += v.x + v.y + v.z + v.w;
            ss += v.x*v.x + v.y*v.y + v.z*v.z + v.w*v.w;
        }
        s  += __shfl_xor(s, 1);  s  += __shfl_xor(s, 2);
        ss += __shfl_xor(ss, 1); ss += __shfl_xor(ss, 2);
        if (q == 0) {
            float m = s * (1.f / Cn);
            mu[p] = m;
            isd[p] = rsqrtf(ss * (1.f / Cn) - m * m + 1e-5f);
        }
    }
    __syncthreads();

    // gate in place: gt[p][c] = ((y-mu)*isd*w + b) * silu-z
    {
        const float4* zp4 = (const float4*)(zs + ((size_t)b * Ln + l0) * Cn);
        const float4* w4  = (const float4*)onw;
        const float4* b4  = (const float4*)onb;
        for (int e4 = t; e4 < 1536; e4 += 512) {
            int p = e4 / 24, c4 = e4 % 24;
            float4 v = *(const float4*)&gt[p * 104 + c4 * 4];
            float4 wv = w4[c4], bv = b4[c4], zv = zp4[e4];
            float m = mu[p], is = isd[p];
            v.x = ((v.x - m) * is * wv.x + bv.x) * zv.x;
            v.y = ((v.y - m) * is * wv.y + bv.y) * zv.y;
            v.z = ((v.z - m) * is * wv.z + bv.z) * zv.z;
            v.w = ((v.w - m) * is * wv.w + bv.w) * zv.w;
            *(float4*)&gt[p * 104 + c4 * 4] = v;
        }
    }

    // fused out_proj GEMM (fp32 vector): out(o,p) = sum_c gt[p][c]*opw[o][c]
    const int og = t & 31, pg = t >> 5;
    float acc[3][4];
#pragma unroll
    for (int i = 0; i < 3; ++i)
#pragma unroll
        for (int r = 0; r < 4; ++r) acc[i][r] = 0.f;

    for (int k0 = 0; k0 < Cn; k0 += 32) {
        __syncthreads();
        for (int e4 = t; e4 < 768; e4 += 512) {
            int o = e4 >> 3, c4 = e4 & 7;
            *(float4*)&wls[o * 36 + c4 * 4] = *(const float4*)&opw[o * Cn + k0 + c4 * 4];
        }
        __syncthreads();
#pragma unroll
        for (int c4 = 0; c4 < 8; ++c4) {
            float4 w0 = *(const float4*)&wls[(og * 3 + 0) * 36 + c4 * 4];
            float4 w1 = *(const float4*)&wls[(og * 3 + 1) * 36 + c4 * 4];
            float4 w2 = *(const float4*)&wls[(og * 3 + 2) * 36 + c4 * 4];
            float4 g0 = *(const float4*)&gt[(pg * 4 + 0) * 104 + k0 + c4 * 4];
            float4 g1 = *(const float4*)&gt[(pg * 4 + 1) * 104 + k0 + c4 * 4];
            float4 g2 = *(const float4*)&gt[(pg * 4 + 2) * 104 + k0 + c4 * 4];
            float4 g3 = *(const float4*)&gt[(pg * 4 + 3) * 104 + k0 + c4 * 4];
#define ACC1(i, wv, r, gv) \
            acc[i][r] = fmaf(wv.x, gv.x, acc[i][r]); \
            acc[i][r] = fmaf(wv.y, gv.y, acc[i][r]); \
            acc[i][r] = fmaf(wv.z, gv.z, acc[i][r]); \
            acc[i][r] = fmaf(wv.w, gv.w, acc[i][r]);
            ACC1(0, w0, 0, g0) ACC1(0, w0, 1, g1) ACC1(0, w0, 2, g2) ACC1(0, w0, 3, g3)
            ACC1(1, w1, 0, g0) ACC1(1, w1, 1, g1) ACC1(1, w1, 2, g2) ACC1(1, w1, 3, g3)
            ACC1(2, w2, 0, g0) ACC1(2, w2, 1, g1) ACC1(2, w2, 2, g2) ACC1(2, w2, 3, g3)
#undef ACC1
        }
    }

    __syncthreads();   // all gt reads done -> reuse gt as outT[o][68]
#pragma unroll
    for (int i = 0; i < 3; ++i)
#pragma unroll
        for (int r = 0; r < 4; ++r)
            gt[(og * 3 + i) * 68 + pg * 4 + r] = acc[i][r];
    __syncthreads();

    {
        float* ob = out + (size_t)b * Cn * Ln + l0;
        for (int e4 = t; e4 < 1536; e4 += 512) {
            int o = e4 >> 4, p4 = e4 & 15;
            float4 v = *(const float4*)&gt[o * 68 + p4 * 4];
            float sc = scw[o];
            v.x *= sc; v.y *= sc; v.z *= sc; v.w *= sc;
            *(float4*)&ob[(size_t)o * Ln + p4 * 4] = v;
        }
    }
}

// ---------------------------------------------------------------------------
extern "C" void kernel_launch(void* const* d_in, const int* in_sizes, int n_in,
                              void* d_out, int out_size, void* d_ws, size_t ws_size,
                              hipStream_t stream)
{
    const float* x     = (const float*)d_in[0];
    const float* ipw   = (const float*)d_in[1];
    const float* cw    = (const float*)d_in[2];
    const float* cb    = (const float*)d_in[3];
    const float* xpw   = (const float*)d_in[4];
    const float* dtw   = (const float*)d_in[5];
    const float* dtb   = (const float*)d_in[6];
    const float* Alogs = (const float*)d_in[7];
    const float* Ds    = (const float*)d_in[8];
    const float* onw   = (const float*)d_in[9];
    const float* onb   = (const float*)d_in[10];
    const float* opw   = (const float*)d_in[11];
    const float* scw   = (const float*)d_in[12];
    float* out = (float*)d_out;

    // Workspace (R13-proven layout, 3A + 3S):
    float* wsp = (float*)d_ws;
    size_t off = 0;
    // xc dead after k_conv -> y0 aliases it
    float* xc   = wsp + off;
    float* y0   = wsp + off; off += (size_t)Bn * Ln * Cn;         // 6.29M
    float* zs   = wsp + off; off += (size_t)Bn * Ln * Cn;         // 6.29M
    float* u    = wsp + off; off += (size_t)Bn * Ln * Cn;         // 6.29M
    // f (fp16, [b][l][k][c]) overlays u byte-exactly per position; each part1
    // block consumes its own u range into LDS (barrier) before overwriting it.
    __half* f   = (__half*)u;
    float* Pc    = wsp + off; off += (size_t)Bn * Kn * NCH * Cn;  // 0.79M
    float* Qc    = wsp + off; off += (size_t)Bn * Kn * NCH * Cn;
    float* hinit = wsp + off; off += (size_t)Bn * Kn * NCH * Cn;

    k_inproj<<<Bn * 256, 128, 0, stream>>>(x, ipw, xc, zs);
    k_conv  <<<(Bn * Ln * 24) / 256, 256, 0, stream>>>(xc, cw, cb, u);
    k_part1 <<<Bn * 512, 384, 0, stream>>>(u, xpw, dtw, dtb, Alogs, Ds,
                                           Pc, Qc, y0, f);
    k_scan2 <<<24, 1024, 0, stream>>>(Pc, Qc, hinit);
    k_merge <<<Bn * 256, 512, 0, stream>>>(y0, f, hinit, zs, onw, onb,
                                           opw, scw, out);
}

// Round 16
// 237.355 us; speedup vs baseline: 1.0635x; 1.0326x over previous
//
#include <hip/hip_runtime.h>
#include <hip/hip_fp16.h>
#include <math.h>

#define Bn 4
#define Cn 96
#define Hn 128
#define Wn 128
#define Ln (Hn*Wn)      // 16384
#define Kn 2
#define Rn 6
#define SC 16           // scan chunk length
#define NCH (Ln/SC)     // 1024 chunks per (b,k)

__device__ __forceinline__ float siluf(float x) { return x / (1.f + __expf(-x)); }
// native-instruction softplus: log1pf is a slow libm polynomial; __logf(1+e)
// is v_log_f32 with abs err < 1e-7 over our range (tolerance 2.5e-2).
__device__ __forceinline__ float softplusf(float x) {
    return fmaxf(x, 0.f) + __logf(1.f + __expf(-fabsf(x)));
}

// ---------------------------------------------------------------------------
// NUMERICS / DETERMINISM LEDGER (empirical):
//   fp32 pipeline + f-fp16 (R1/R3/R13)   = 0.001953125, BIT-STABLE. PASSED.
//   f16-MFMA out_proj: NONDETERMINISTIC (0.0117-0.0273) -> ABANDONED.
//   zs/y0 fp16: FAILED (0.031-0.037) -> fp32 forever.
// SPEED LEDGER for k_inproj (macro-tiling is a LOCAL OPTIMUM at R13):
//   R13: 128pos x 192out, 256thr, 2 blk/CU             = 51.5 us  BEST
//   R14: 64pos tile (4 blk/CU)                          = 66.4 us  WORSE
//   R15: 96-out half-split (128thr blocks)              = 56.5 us  WORSE
// R16 = R13 verbatim + ONE index bijection in the w-staging loop:
//   old: o=idx%192, k=idx/192 -> lanes read 384B-strided (64 lines/instr)
//   new: k=idx&31,  o=idx>>5  -> 32-lane contiguous 128B segments (2 lines)
// Same (k,o) set, same wls slots -> BIT-IDENTICAL output.
// ---------------------------------------------------------------------------

// ---------------------------------------------------------------------------
// Kernel A: in_proj GEMM, fp32 vector (R13 + coalesced w-staging).
// x (B,C,L) -> xc (B,L,C) fp32, zs = silu(z) (B,L,C) fp32.
// ---------------------------------------------------------------------------
__global__ __launch_bounds__(256, 3) void k_inproj(
    const float* __restrict__ x, const float* __restrict__ ipw,
    float* __restrict__ xc, float* __restrict__ zs)
{
    __shared__ float smem[4096 + 6272];
    float* xls = smem;
    float* wls = smem + 4096;
    float* stage = smem;

    const int t  = threadIdx.x;
    const int b  = blockIdx.x >> 7;
    const int l0 = (blockIdx.x & 127) << 7;
    const int tx = t & 15;
    const int ty = t >> 4;

    float acc[12][8];
#pragma unroll
    for (int i = 0; i < 12; ++i)
#pragma unroll
        for (int j = 0; j < 8; ++j) acc[i][j] = 0.f;

    const float* xbase = x + (size_t)b * Cn * Ln + l0;

    for (int k0 = 0; k0 < Cn; k0 += 32) {
        if (k0) __syncthreads();
        {
            int idx = t;
#pragma unroll
            for (int q = 0; q < 4; ++q, idx += 256) {
                int k = idx >> 5, p4 = idx & 31;
                *(float4*)&xls[k * 128 + p4 * 4] =
                    *(const float4*)&xbase[(size_t)(k0 + k) * Ln + p4 * 4];
            }
        }
        // w chunk: coalesced -- 32 consecutive k per o-row (128B segments)
        for (int idx = t; idx < 32 * 192; idx += 256) {
            int k = idx & 31, o = idx >> 5;
            wls[k * 196 + o] = ipw[o * Cn + k0 + k];
        }
        __syncthreads();

#pragma unroll 2
        for (int kk = 0; kk < 32; ++kk) {
            float4 xv0 = *(const float4*)&xls[kk * 128 + tx * 4];
            float4 xv1 = *(const float4*)&xls[kk * 128 + 64 + tx * 4];
            const float* wrow = &wls[kk * 196 + ty * 12];
            float4 w0 = *(const float4*)&wrow[0];
            float4 w1 = *(const float4*)&wrow[4];
            float4 w2 = *(const float4*)&wrow[8];
            float wv[12] = {w0.x,w0.y,w0.z,w0.w,w1.x,w1.y,w1.z,w1.w,w2.x,w2.y,w2.z,w2.w};
            float xa[8]  = {xv0.x,xv0.y,xv0.z,xv0.w,xv1.x,xv1.y,xv1.z,xv1.w};
#pragma unroll
            for (int i = 0; i < 12; ++i)
#pragma unroll
                for (int j = 0; j < 8; ++j)
                    acc[i][j] = fmaf(wv[i], xa[j], acc[i][j]);
        }
    }

    const size_t tilebase = (size_t)b * Ln + l0;
#pragma unroll
    for (int half_ = 0; half_ < 2; ++half_) {
        __syncthreads();
        if (ty < 8) {
#pragma unroll
            for (int j = 0; j < 4; ++j)
#pragma unroll
                for (int i = 0; i < 12; ++i)
                    stage[(tx * 4 + j) * 100 + ty * 12 + i] = acc[i][half_ * 4 + j];
        }
        __syncthreads();
        {
            float4* dst = (float4*)(xc + (tilebase + half_ * 64) * Cn);
            for (int idx = t; idx < 1536; idx += 256) {
                int p = idx / 24, c4 = idx % 24;
                dst[idx] = *(const float4*)&stage[p * 100 + c4 * 4];
            }
        }
        __syncthreads();
        if (ty >= 8) {
#pragma unroll
            for (int j = 0; j < 4; ++j)
#pragma unroll
                for (int i = 0; i < 12; ++i)
                    stage[(tx * 4 + j) * 100 + (ty - 8) * 12 + i] = siluf(acc[i][half_ * 4 + j]);
        }
        __syncthreads();
        {
            float4* dst = (float4*)(zs + (tilebase + half_ * 64) * Cn);
            for (int idx = t; idx < 1536; idx += 256) {
                int p = idx / 24, c4 = idx % 24;
                dst[idx] = *(const float4*)&stage[p * 100 + c4 * 4];
            }
        }
    }
}

// ---------------------------------------------------------------------------
// Kernel B: depthwise 3x3 conv (SAME) + bias + SiLU, float4 over channels.
// ---------------------------------------------------------------------------
__global__ __launch_bounds__(256) void k_conv(
    const float* __restrict__ xc, const float* __restrict__ cw,
    const float* __restrict__ cb, float* __restrict__ u)
{
    __shared__ float cws[9 * 96];   // [tap][c]
    for (int i = threadIdx.x; i < 864; i += 256) {
        int cc = i % 96, tap = i / 96;
        cws[tap * 96 + cc] = cw[cc * 9 + tap];
    }
    __syncthreads();

    const int e   = blockIdx.x * 256 + threadIdx.x;
    const int c4  = e % 24;
    const int pos = e / 24;
    const int l   = pos % Ln;
    const int b   = pos / Ln;
    const int h   = l >> 7, w = l & 127;
    const int c   = c4 * 4;

    float4 acc = *(const float4*)&cb[c];
#pragma unroll
    for (int dh = -1; dh <= 1; ++dh) {
        int hh = h + dh;
        if (hh < 0 || hh >= Hn) continue;
#pragma unroll
        for (int dw = -1; dw <= 1; ++dw) {
            int ww = w + dw;
            if (ww < 0 || ww >= Wn) continue;
            float4 wv = *(const float4*)&cws[((dh + 1) * 3 + (dw + 1)) * 96 + c];
            float4 xv = *(const float4*)&xc[((size_t)b * Ln + (hh << 7) + ww) * Cn + c];
            acc.x = fmaf(wv.x, xv.x, acc.x);
            acc.y = fmaf(wv.y, xv.y, acc.y);
            acc.z = fmaf(wv.z, xv.z, acc.z);
            acc.w = fmaf(wv.w, xv.w, acc.w);
        }
    }
    float4 r;
    r.x = siluf(acc.x); r.y = siluf(acc.y); r.z = siluf(acc.z); r.w = siluf(acc.w);
    *(float4*)&u[((size_t)b * Ln + l) * Cn + c] = r;
}

// ---------------------------------------------------------------------------
// Kernel C (k_part1): R13-proven (GEMV broadcast remap, fp32 y0, f fp16).
// ---------------------------------------------------------------------------
__global__ __launch_bounds__(384, 4) void k_part1(
    const float* __restrict__ u, const float* __restrict__ xpw,
    const float* __restrict__ dtw, const float* __restrict__ dtb,
    const float* __restrict__ Alogs, const float* __restrict__ Ds,
    float* __restrict__ Pc, float* __restrict__ Qc,
    float* __restrict__ y0, __half* __restrict__ f)
{
    __shared__ float uls[32 * 100];  // [p][c] pad 100; reused as y-merge buffer
    __shared__ float xd[32 * 16];    // [p][dd] dd=k*8+d
    __shared__ float dsum[96];
    const int t  = threadIdx.x;
    const int j  = blockIdx.x & 511;
    const int b  = blockIdx.x >> 9;
    const int l0 = j << 5;

    {
        const float4* up4 = (const float4*)(u + ((size_t)b * Ln + l0) * Cn);
        for (int e4 = t; e4 < 768; e4 += 384) {
            int p = e4 / 24, c4 = e4 % 24;
            *(float4*)&uls[p * 100 + c4 * 4] = up4[e4];
        }
    }
    if (t < 96) dsum[t] = Ds[t] + Ds[Cn + t];
    __syncthreads();   // all u loads in LDS before any f-store below (alias!)

    for (int dp = t; dp < 512; dp += 384) {
        int p = dp & 31, dd = dp >> 5;     // broadcast-friendly remap
        const float4* wr = (const float4*)(xpw + dd * Cn);
        const float4* ur = (const float4*)&uls[p * 100];
        float acc = 0.f;
#pragma unroll
        for (int c4 = 0; c4 < 24; ++c4) {
            float4 w = wr[c4], v = ur[c4];
            acc = fmaf(w.x, v.x, acc); acc = fmaf(w.y, v.y, acc);
            acc = fmaf(w.z, v.z, acc); acc = fmaf(w.w, v.w, acc);
        }
        xd[p * 16 + dd] = acc;
    }
    __syncthreads();

    const int c  = t % 96;
    const int ci = (t / 96) & 1;
    const int k  = t / 192;
    const int bk = b * Kn + k;
    const float Av = -__expf(Alogs[k * Cn + c]);
    const float bias = dtb[k * Cn + c];
    const float dsc = dsum[c];
    float dtwr[Rn];
#pragma unroll
    for (int r = 0; r < Rn; ++r) dtwr[r] = dtw[(k * Cn + c) * Rn + r];

    const int chunk = (k == 0) ? (2 * j + ci) : (1022 - 2 * j + ci);
    const int xoff = k * 8;
    __half* fkc = f + ((size_t)(b * Ln + l0) * 2 + k) * Cn + c;

    float h = 0.f, cp = 1.f;
    float yreg[SC];
#pragma unroll
    for (int hf = 0; hf < 2; ++hf) {
        float dAv[8], dBu[8], Cl[8], uv[8];
#pragma unroll
        for (int i = 0; i < 8; ++i) {
            const int ii = hf * 8 + i;
            const int p = (k == 0) ? (ci * 16 + ii) : ((1 - ci) * 16 + (15 - ii));
            const float* xr = &xd[p * 16 + xoff];
            float de = bias;
#pragma unroll
            for (int r = 0; r < Rn; ++r) de = fmaf(dtwr[r], xr[r], de);
            de = softplusf(de);
            uv[i]  = uls[p * 100 + c];
            dAv[i] = __expf(de * Av);
            dBu[i] = de * uv[i] * xr[6];
            Cl[i]  = xr[7];
        }
#pragma unroll
        for (int i = 0; i < 8; ++i) {
            const int ii = hf * 8 + i;
            const int p = (k == 0) ? (ci * 16 + ii) : ((1 - ci) * 16 + (15 - ii));
            h  = fmaf(dAv[i], h, dBu[i]);
            cp *= dAv[i];
            yreg[ii] = (k == 0) ? fmaf(dsc, uv[i], h * Cl[i]) : (h * Cl[i]);
            fkc[(size_t)p * (2 * Cn)] = __float2half(cp * Cl[i]);
        }
    }
    {
        const size_t cidx = ((size_t)bk * NCH + chunk) * Cn + c;
        Pc[cidx] = cp;
        Qc[cidx] = h;
    }

    __syncthreads();   // all uls reads done
    if (k == 0) {
#pragma unroll
        for (int i = 0; i < SC; ++i) {
            int p = ci * 16 + i;
            uls[p * 100 + c] = yreg[i];
        }
    }
    __syncthreads();
    if (k == 1) {
#pragma unroll
        for (int i = 0; i < SC; ++i) {
            int p = (1 - ci) * 16 + (15 - i);
            uls[p * 100 + c] += yreg[i];
        }
    }
    __syncthreads();
    {
        float4* y4 = (float4*)(y0 + ((size_t)b * Ln + l0) * Cn);
        for (int e4 = t; e4 < 768; e4 += 384) {
            int p = e4 / 24, c4 = e4 % 24;
            y4[e4] = *(const float4*)&uls[p * 100 + c4 * 4];
        }
    }
}

// ---------------------------------------------------------------------------
// Kernel D: hierarchical carry scan (unchanged). 768 series x 1024 chunks.
// ---------------------------------------------------------------------------
__global__ __launch_bounds__(1024) void k_scan2(
    const float* __restrict__ Pc, const float* __restrict__ Qc,
    float* __restrict__ hinit)
{
    __shared__ float Pg[32][33], Qg[32][33], gini[32][33];
    const int bk    = blockIdx.x / 3;
    const int cbase = (blockIdx.x % 3) * 32;
    const int t = threadIdx.x;
    const int c = t & 31, g = t >> 5;

    const size_t base = ((size_t)bk * NCH + g * 32) * Cn + cbase + c;
    float P = 1.f, Q = 0.f;
    for (int j = 0; j < 32; ++j) {
        size_t idx = base + (size_t)j * Cn;
        float p_ = Pc[idx], q_ = Qc[idx];
        Q = fmaf(p_, Q, q_);
        P *= p_;
    }
    Pg[g][c] = P; Qg[g][c] = Q;
    __syncthreads();
    if (t < 32) {
        float h = 0.f;
        for (int gg = 0; gg < 32; ++gg) {
            gini[gg][t] = h;
            h = fmaf(Pg[gg][t], h, Qg[gg][t]);
        }
    }
    __syncthreads();
    float h = gini[g][c];
    for (int j = 0; j < 32; ++j) {
        size_t idx = base + (size_t)j * Cn;
        hinit[idx] = h;
        h = fmaf(Pc[idx], h, Qc[idx]);
    }
}

// ---------------------------------------------------------------------------
// Kernel E (k_merge): streaming merge + LN + gate + fused fp32 out_proj GEMM
// (R13-proven, deterministic 0.00195).  No g round-trip to HBM.
// ---------------------------------------------------------------------------
__global__ __launch_bounds__(512) void k_merge(
    const float* __restrict__ y0, const __half* __restrict__ f,
    const float* __restrict__ hinit, const float* __restrict__ zs,
    const float* __restrict__ onw, const float* __restrict__ onb,
    const float* __restrict__ opw, const float* __restrict__ scw,
    float* __restrict__ out)
{
    __shared__ float gt[64 * 104];   // y -> gated g -> reused as outT[o][68]
    __shared__ float wls[96 * 36];   // opw chunk [o][32] pad 36
    __shared__ float h0s[4 * 96], h1s[4 * 96];
    __shared__ float mu[64], isd[64];
    const int t  = threadIdx.x;
    const int j  = blockIdx.x & 255;
    const int b  = blockIdx.x >> 8;
    const int l0 = j << 6;

    for (int idx = t; idx < 768; idx += 512) {
        if (idx < 384) {
            int q = idx / 96, c = idx % 96;
            h0s[q * 96 + c] = hinit[((size_t)(b * 2 + 0) * NCH + 4 * j + q) * Cn + c];
        } else {
            int i2 = idx - 384;
            int q = i2 / 96, c = i2 % 96;
            h1s[q * 96 + c] = hinit[((size_t)(b * 2 + 1) * NCH + (1023 - 4 * j - q)) * Cn + c];
        }
    }
    __syncthreads();

    // elementwise merge: y = y0 + h0*f0 + h1*f1  -> gt[p][c]
    {
        const float4* y4 = (const float4*)(y0 + ((size_t)b * Ln + l0) * Cn);
        const __half* fb = f + (size_t)(b * Ln + l0) * 2 * Cn;
        for (int e4 = t; e4 < 1536; e4 += 512) {
            int p = e4 / 24, c4 = e4 % 24;
            float4 yv = y4[e4];
            const __half* fp0 = fb + (size_t)p * (2 * Cn) + c4 * 4;
            const __half2* f0h = (const __half2*)fp0;
            const __half2* f1h = (const __half2*)(fp0 + Cn);
            float2 fa0 = __half22float2(f0h[0]);
            float2 fa1 = __half22float2(f0h[1]);
            float2 fb0 = __half22float2(f1h[0]);
            float2 fb1 = __half22float2(f1h[1]);
            const float4 h0v = *(const float4*)&h0s[(p >> 4) * 96 + c4 * 4];
            const float4 h1v = *(const float4*)&h1s[(p >> 4) * 96 + c4 * 4];
            yv.x = fmaf(h0v.x, fa0.x, fmaf(h1v.x, fb0.x, yv.x));
            yv.y = fmaf(h0v.y, fa0.y, fmaf(h1v.y, fb0.y, yv.y));
            yv.z = fmaf(h0v.z, fa1.x, fmaf(h1v.z, fb1.x, yv.z));
            yv.w = fmaf(h0v.w, fa1.y, fmaf(h1v.w, fb1.y, yv.w));
            *(float4*)&gt[p * 104 + c4 * 4] = yv;
        }
    }
    __syncthreads();

    if (t < 256) {
        const int p = t >> 2, q = t & 3;
        const float4* row = (const float4*)&gt[p * 104 + q * 24];
        float s = 0.f, ss = 0.f;
#pragma unroll
        for (int i = 0; i < 6; ++i) {
            float4 v = row[i];
            s  += v.x + v.y + v.z + v.w;
            ss += v.x*v.x + v.y*v.y + v.z*v.z + v.w*v.w;
        }
        s  += __shfl_xor(s, 1);  s  += __shfl_xor(s, 2);
        ss += __shfl_xor(ss, 1); ss += __shfl_xor(ss, 2);
        if (q == 0) {
            float m = s * (1.f / Cn);
            mu[p] = m;
            isd[p] = rsqrtf(ss * (1.f / Cn) - m * m + 1e-5f);
        }
    }
    __syncthreads();

    // gate in place: gt[p][c] = ((y-mu)*isd*w + b) * silu-z
    {
        const float4* zp4 = (const float4*)(zs + ((size_t)b * Ln + l0) * Cn);
        const float4* w4  = (const float4*)onw;
        const float4* b4  = (const float4*)onb;
        for (int e4 = t; e4 < 1536; e4 += 512) {
            int p = e4 / 24, c4 = e4 % 24;
            float4 v = *(const float4*)&gt[p * 104 + c4 * 4];
            float4 wv = w4[c4], bv = b4[c4], zv = zp4[e4];
            float m = mu[p], is = isd[p];
            v.x = ((v.x - m) * is * wv.x + bv.x) * zv.x;
            v.y = ((v.y - m) * is * wv.y + bv.y) * zv.y;
            v.z = ((v.z - m) * is * wv.z + bv.z) * zv.z;
            v.w = ((v.w - m) * is * wv.w + bv.w) * zv.w;
            *(float4*)&gt[p * 104 + c4 * 4] = v;
        }
    }

    // fused out_proj GEMM (fp32 vector): out(o,p) = sum_c gt[p][c]*opw[o][c]
    const int og = t & 31, pg = t >> 5;
    float acc[3][4];
#pragma unroll
    for (int i = 0; i < 3; ++i)
#pragma unroll
        for (int r = 0; r < 4; ++r) acc[i][r] = 0.f;

    for (int k0 = 0; k0 < Cn; k0 += 32) {
        __syncthreads();
        for (int e4 = t; e4 < 768; e4 += 512) {
            int o = e4 >> 3, c4 = e4 & 7;
            *(float4*)&wls[o * 36 + c4 * 4] = *(const float4*)&opw[o * Cn + k0 + c4 * 4];
        }
        __syncthreads();
#pragma unroll
        for (int c4 = 0; c4 < 8; ++c4) {
            float4 w0 = *(const float4*)&wls[(og * 3 + 0) * 36 + c4 * 4];
            float4 w1 = *(const float4*)&wls[(og * 3 + 1) * 36 + c4 * 4];
            float4 w2 = *(const float4*)&wls[(og * 3 + 2) * 36 + c4 * 4];
            float4 g0 = *(const float4*)&gt[(pg * 4 + 0) * 104 + k0 + c4 * 4];
            float4 g1 = *(const float4*)&gt[(pg * 4 + 1) * 104 + k0 + c4 * 4];
            float4 g2 = *(const float4*)&gt[(pg * 4 + 2) * 104 + k0 + c4 * 4];
            float4 g3 = *(const float4*)&gt[(pg * 4 + 3) * 104 + k0 + c4 * 4];
#define ACC1(i, wv, r, gv) \
            acc[i][r] = fmaf(wv.x, gv.x, acc[i][r]); \
            acc[i][r] = fmaf(wv.y, gv.y, acc[i][r]); \
            acc[i][r] = fmaf(wv.z, gv.z, acc[i][r]); \
            acc[i][r] = fmaf(wv.w, gv.w, acc[i][r]);
            ACC1(0, w0, 0, g0) ACC1(0, w0, 1, g1) ACC1(0, w0, 2, g2) ACC1(0, w0, 3, g3)
            ACC1(1, w1, 0, g0) ACC1(1, w1, 1, g1) ACC1(1, w1, 2, g2) ACC1(1, w1, 3, g3)
            ACC1(2, w2, 0, g0) ACC1(2, w2, 1, g1) ACC1(2, w2, 2, g2) ACC1(2, w2, 3, g3)
#undef ACC1
        }
    }

    __syncthreads();   // all gt reads done -> reuse gt as outT[o][68]
#pragma unroll
    for (int i = 0; i < 3; ++i)
#pragma unroll
        for (int r = 0; r < 4; ++r)
            gt[(og * 3 + i) * 68 + pg * 4 + r] = acc[i][r];
    __syncthreads();

    {
        float* ob = out + (size_t)b * Cn * Ln + l0;
        for (int e4 = t; e4 < 1536; e4 += 512) {
            int o = e4 >> 4, p4 = e4 & 15;
            float4 v = *(const float4*)&gt[o * 68 + p4 * 4];
            float sc = scw[o];
            v.x *= sc; v.y *= sc; v.z *= sc; v.w *= sc;
            *(float4*)&ob[(size_t)o * Ln + p4 * 4] = v;
        }
    }
}

// ---------------------------------------------------------------------------
extern "C" void kernel_launch(void* const* d_in, const int* in_sizes, int n_in,
                              void* d_out, int out_size, void* d_ws, size_t ws_size,
                              hipStream_t stream)
{
    const float* x     = (const float*)d_in[0];
    const float* ipw   = (const float*)d_in[1];
    const float* cw    = (const float*)d_in[2];
    const float* cb    = (const float*)d_in[3];
    const float* xpw   = (const float*)d_in[4];
    const float* dtw   = (const float*)d_in[5];
    const float* dtb   = (const float*)d_in[6];
    const float* Alogs = (const float*)d_in[7];
    const float* Ds    = (const float*)d_in[8];
    const float* onw   = (const float*)d_in[9];
    const float* onb   = (const float*)d_in[10];
    const float* opw   = (const float*)d_in[11];
    const float* scw   = (const float*)d_in[12];
    float* out = (float*)d_out;

    // Workspace (R13-proven layout, 3A + 3S):
    float* wsp = (float*)d_ws;
    size_t off = 0;
    // xc dead after k_conv -> y0 aliases it
    float* xc   = wsp + off;
    float* y0   = wsp + off; off += (size_t)Bn * Ln * Cn;         // 6.29M
    float* zs   = wsp + off; off += (size_t)Bn * Ln * Cn;         // 6.29M
    float* u    = wsp + off; off += (size_t)Bn * Ln * Cn;         // 6.29M
    // f (fp16, [b][l][k][c]) overlays u byte-exactly per position; each part1
    // block consumes its own u range into LDS (barrier) before overwriting it.
    __half* f   = (__half*)u;
    float* Pc    = wsp + off; off += (size_t)Bn * Kn * NCH * Cn;  // 0.79M
    float* Qc    = wsp + off; off += (size_t)Bn * Kn * NCH * Cn;
    float* hinit = wsp + off; off += (size_t)Bn * Kn * NCH * Cn;

    k_inproj<<<Bn * 128, 256, 0, stream>>>(x, ipw, xc, zs);
    k_conv  <<<(Bn * Ln * 24) / 256, 256, 0, stream>>>(xc, cw, cb, u);
    k_part1 <<<Bn * 512, 384, 0, stream>>>(u, xpw, dtw, dtb, Alogs, Ds,
                                           Pc, Qc, y0, f);
    k_scan2 <<<24, 1024, 0, stream>>>(Pc, Qc, hinit);
    k_merge <<<Bn * 256, 512, 0, stream>>>(y0, f, hinit, zs, onw, onb,
                                           opw, scw, out);
}